// Round 1
// baseline (65.789 us; speedup 1.0000x reference)
//
#include <hip/hip_runtime.h>
#include <math.h>

#define BATCH 64
#define SEQ 4096
#define HID 256
#define NBLK 16                          // S-chunks per batch
#define ROWS_PER_BLK (SEQ / NBLK)        // 256 rows per block
#define THREADS 256
#define NWAVE (THREADS / 64)             // 4 waves
#define ROWS_PER_WAVE (ROWS_PER_BLK / NWAVE)  // 64 rows per wave

// Kernel 1: single pass over trg. Per batch-chunk, compute online-softmax
// partials: running max m, denom l, and unnormalized weighted pooled[256].
__global__ __launch_bounds__(THREADS) void pool_pass(
        const float* __restrict__ trg,
        float* __restrict__ ws_m,
        float* __restrict__ ws_l,
        float* __restrict__ ws_p) {
    const int b     = blockIdx.x / NBLK;
    const int chunk = blockIdx.x % NBLK;
    const int wave  = threadIdx.x >> 6;
    const int lane  = threadIdx.x & 63;

    const float* base = trg + ((size_t)b * SEQ + (size_t)chunk * ROWS_PER_BLK) * HID;

    float m = -INFINITY, l = 0.f;
    float a0 = 0.f, a1 = 0.f, a2 = 0.f, a3 = 0.f;  // pooled elems lane*4..+3

    const int r0 = wave * ROWS_PER_WAVE;
    #pragma unroll 4
    for (int r = 0; r < ROWS_PER_WAVE; ++r) {
        const float4 v = *reinterpret_cast<const float4*>(
            base + (size_t)(r0 + r) * HID + lane * 4);
        float ss = v.x * v.x + v.y * v.y + v.z * v.z + v.w * v.w;
        #pragma unroll
        for (int off = 32; off > 0; off >>= 1)
            ss += __shfl_xor(ss, off, 64);
        const float nrm   = sqrtf(ss);           // same on all 64 lanes
        const float m_new = fmaxf(m, nrm);
        const float scale = expf(m - m_new);     // m=-inf first iter -> 0
        const float p     = expf(nrm - m_new);
        l  = l  * scale + p;
        a0 = a0 * scale + p * v.x;
        a1 = a1 * scale + p * v.y;
        a2 = a2 * scale + p * v.z;
        a3 = a3 * scale + p * v.w;
        m  = m_new;
    }

    // Block combine across 4 waves.
    __shared__ float s_m[NWAVE];
    __shared__ float s_l[NWAVE];
    __shared__ float s_p[NWAVE][HID];
    if (lane == 0) s_m[wave] = m;
    __syncthreads();
    float m_blk = s_m[0];
    #pragma unroll
    for (int w = 1; w < NWAVE; ++w) m_blk = fmaxf(m_blk, s_m[w]);
    const float sc = expf(m - m_blk);            // wave-uniform
    if (lane == 0) s_l[wave] = l * sc;
    s_p[wave][lane * 4 + 0] = a0 * sc;
    s_p[wave][lane * 4 + 1] = a1 * sc;
    s_p[wave][lane * 4 + 2] = a2 * sc;
    s_p[wave][lane * 4 + 3] = a3 * sc;
    __syncthreads();

    const int j = threadIdx.x;
    float pj = 0.f;
    #pragma unroll
    for (int w = 0; w < NWAVE; ++w) pj += s_p[w][j];
    const int pidx = b * NBLK + chunk;
    ws_p[(size_t)pidx * HID + j] = pj;
    if (j == 0) {
        ws_m[pidx] = m_blk;
        float lt = 0.f;
        #pragma unroll
        for (int w = 0; w < NWAVE; ++w) lt += s_l[w];
        ws_l[pidx] = lt;
    }
}

// Kernel 2: combine NBLK partials per batch, normalize, then the tiny MLP:
// h = relu(pooled @ W1 + b1); out[b] = h @ W2 + b2.
__global__ __launch_bounds__(THREADS) void finish_pass(
        const float* __restrict__ ws_m,
        const float* __restrict__ ws_l,
        const float* __restrict__ ws_p,
        const float* __restrict__ W1,
        const float* __restrict__ b1,
        const float* __restrict__ W2,
        const float* __restrict__ b2,
        float* __restrict__ out) {
    const int b = blockIdx.x;
    const int j = threadIdx.x;  // 0..255: owns pooled[j], h[j]

    __shared__ float s_m[NBLK];
    __shared__ float s_l[NBLK];
    __shared__ float s_pooled[HID];
    __shared__ float s_red[NWAVE];

    if (j < NBLK) {
        s_m[j] = ws_m[b * NBLK + j];
        s_l[j] = ws_l[b * NBLK + j];
    }
    __syncthreads();

    float m = s_m[0];
    #pragma unroll
    for (int i = 1; i < NBLK; ++i) m = fmaxf(m, s_m[i]);

    float l = 0.f, pj = 0.f;
    #pragma unroll
    for (int i = 0; i < NBLK; ++i) {
        const float sc = expf(s_m[i] - m);
        l  += s_l[i] * sc;
        pj += ws_p[(size_t)(b * NBLK + i) * HID + j] * sc;
    }
    const float pooled = pj / l;
    s_pooled[j] = pooled;
    __syncthreads();

    // FC1 column j: h = relu(sum_k pooled[k] * W1[k][j] + b1[j])
    float h = b1[j];
    #pragma unroll 8
    for (int k = 0; k < HID; ++k)
        h = fmaf(s_pooled[k], W1[k * HID + j], h);
    h = fmaxf(h, 0.f);

    // FC2: out[b] = sum_j h[j] * W2[j] + b2
    float v = h * W2[j];
    #pragma unroll
    for (int off = 32; off > 0; off >>= 1)
        v += __shfl_xor(v, off, 64);
    if ((j & 63) == 0) s_red[j >> 6] = v;
    __syncthreads();
    if (j == 0)
        out[b] = s_red[0] + s_red[1] + s_red[2] + s_red[3] + b2[0];
}

extern "C" void kernel_launch(void* const* d_in, const int* in_sizes, int n_in,
                              void* d_out, int out_size, void* d_ws, size_t ws_size,
                              hipStream_t stream) {
    const float* trg = (const float*)d_in[0];
    // d_in[1] = src: unused (n_layers = 0)
    const float* W1  = (const float*)d_in[2];
    const float* b1  = (const float*)d_in[3];
    const float* W2  = (const float*)d_in[4];
    const float* b2  = (const float*)d_in[5];
    float* out = (float*)d_out;

    // Workspace layout: m[B*NBLK] | l[B*NBLK] | pooled[B*NBLK*HID]
    float* ws_m = (float*)d_ws;
    float* ws_l = ws_m + BATCH * NBLK;
    float* ws_p = ws_l + BATCH * NBLK;

    pool_pass<<<dim3(BATCH * NBLK), THREADS, 0, stream>>>(trg, ws_m, ws_l, ws_p);
    finish_pass<<<dim3(BATCH), THREADS, 0, stream>>>(ws_m, ws_l, ws_p,
                                                     W1, b1, W2, b2, out);
}

// Round 2
// 58.095 us; speedup vs baseline: 1.1324x; 1.1324x over previous
//
#include <hip/hip_runtime.h>
#include <math.h>

#define BATCH 64
#define SEQ 4096
#define HID 256
#define NBLK 32                          // S-chunks per batch
#define ROWS_PER_BLK (SEQ / NBLK)        // 128 rows per block
#define THREADS 256
#define NWAVE (THREADS / 64)             // 4 waves
#define NGROUP 16                        // 16-lane groups per block
#define ITERS (ROWS_PER_BLK / NGROUP)    // 8 serial iterations

// Kernel 1: single pass over trg. Each 16-lane group owns one row per
// iteration: 4 float4 loads/lane cover the 256-col row across 16 lanes.
// Online softmax with defer-max (rescale only when nrm > m + 8).
__global__ __launch_bounds__(THREADS) void pool_pass(
        const float* __restrict__ trg,
        float* __restrict__ ws_m,
        float* __restrict__ ws_l,
        float* __restrict__ ws_p) {
    const int b     = blockIdx.x / NBLK;
    const int chunk = blockIdx.x % NBLK;
    const int tid   = threadIdx.x;
    const int gid   = tid >> 4;          // 0..15: group id within block
    const int sub   = tid & 15;          // lane within group

    const float* base = trg + ((size_t)b * SEQ + (size_t)chunk * ROWS_PER_BLK) * HID;

    float m = -INFINITY, l = 0.f;
    float4 acc[4];
    #pragma unroll
    for (int q = 0; q < 4; ++q) acc[q] = make_float4(0.f, 0.f, 0.f, 0.f);

    #pragma unroll 2
    for (int t = 0; t < ITERS; ++t) {
        const int r = t * NGROUP + gid;
        const float* rp = base + (size_t)r * HID + sub * 4;
        float4 v[4];
        #pragma unroll
        for (int q = 0; q < 4; ++q)
            v[q] = *reinterpret_cast<const float4*>(rp + q * 64);

        float ss = 0.f;
        #pragma unroll
        for (int q = 0; q < 4; ++q)
            ss += v[q].x * v[q].x + v[q].y * v[q].y
                + v[q].z * v[q].z + v[q].w * v[q].w;
        // reduce within the 16-lane group (xor masks < 16 stay in-group)
        ss += __shfl_xor(ss, 1, 64);
        ss += __shfl_xor(ss, 2, 64);
        ss += __shfl_xor(ss, 4, 64);
        ss += __shfl_xor(ss, 8, 64);
        const float nrm = sqrtf(ss);     // uniform across the 16-lane group

        if (nrm > m + 8.f) {             // defer-max: rare after warm-up
            const float sc = __expf(m - nrm);   // 0 on first iter (m=-inf)
            l *= sc;
            #pragma unroll
            for (int q = 0; q < 4; ++q) {
                acc[q].x *= sc; acc[q].y *= sc;
                acc[q].z *= sc; acc[q].w *= sc;
            }
            m = nrm;
        }
        const float p = __expf(nrm - m); // <= e^8, fp32-safe
        l += p;
        #pragma unroll
        for (int q = 0; q < 4; ++q) {
            acc[q].x = fmaf(p, v[q].x, acc[q].x);
            acc[q].y = fmaf(p, v[q].y, acc[q].y);
            acc[q].z = fmaf(p, v[q].z, acc[q].z);
            acc[q].w = fmaf(p, v[q].w, acc[q].w);
        }
    }

    // Block combine across 16 groups.
    __shared__ float s_m[NGROUP];
    __shared__ float s_l[NGROUP];
    __shared__ float s_p[NGROUP][HID];
    if (sub == 0) s_m[gid] = m;
    __syncthreads();
    float m_blk = s_m[0];
    #pragma unroll
    for (int g = 1; g < NGROUP; ++g) m_blk = fmaxf(m_blk, s_m[g]);
    const float sc = __expf(m - m_blk); // group-uniform
    if (sub == 0) s_l[gid] = l * sc;
    #pragma unroll
    for (int q = 0; q < 4; ++q) {
        float4 a = acc[q];
        a.x *= sc; a.y *= sc; a.z *= sc; a.w *= sc;
        *reinterpret_cast<float4*>(&s_p[gid][q * 64 + sub * 4]) = a;
    }
    __syncthreads();

    const int j = tid;                   // 0..255: output column
    float pj = 0.f;
    #pragma unroll
    for (int g = 0; g < NGROUP; ++g) pj += s_p[g][j];
    const int pidx = b * NBLK + chunk;
    ws_p[(size_t)pidx * HID + j] = pj;
    if (j == 0) {
        ws_m[pidx] = m_blk;
        float lt = 0.f;
        #pragma unroll
        for (int g = 0; g < NGROUP; ++g) lt += s_l[g];
        ws_l[pidx] = lt;
    }
}

// Kernel 2: combine NBLK partials per batch, normalize, tiny MLP.
__global__ __launch_bounds__(THREADS) void finish_pass(
        const float* __restrict__ ws_m,
        const float* __restrict__ ws_l,
        const float* __restrict__ ws_p,
        const float* __restrict__ W1,
        const float* __restrict__ b1,
        const float* __restrict__ W2,
        const float* __restrict__ b2,
        float* __restrict__ out) {
    const int b = blockIdx.x;
    const int j = threadIdx.x;  // 0..255: owns pooled[j], h[j]

    __shared__ float s_m[NBLK];
    __shared__ float s_l[NBLK];
    __shared__ float s_pooled[HID];
    __shared__ float s_red[NWAVE];

    if (j < NBLK) {
        s_m[j] = ws_m[b * NBLK + j];
        s_l[j] = ws_l[b * NBLK + j];
    }
    __syncthreads();

    float m = s_m[0];
    #pragma unroll
    for (int i = 1; i < NBLK; ++i) m = fmaxf(m, s_m[i]);

    float l = 0.f, pj = 0.f;
    #pragma unroll 8
    for (int i = 0; i < NBLK; ++i) {
        const float sc = __expf(s_m[i] - m);
        l  += s_l[i] * sc;
        pj += ws_p[(size_t)(b * NBLK + i) * HID + j] * sc;
    }
    const float pooled = pj / l;
    s_pooled[j] = pooled;
    __syncthreads();

    // FC1 column j: h = relu(sum_k pooled[k] * W1[k][j] + b1[j])
    float h = b1[j];
    #pragma unroll 8
    for (int k = 0; k < HID; ++k)
        h = fmaf(s_pooled[k], W1[k * HID + j], h);
    h = fmaxf(h, 0.f);

    // FC2: out[b] = sum_j h[j] * W2[j] + b2
    float v = h * W2[j];
    #pragma unroll
    for (int off = 32; off > 0; off >>= 1)
        v += __shfl_xor(v, off, 64);
    if ((j & 63) == 0) s_red[j >> 6] = v;
    __syncthreads();
    if (j == 0)
        out[b] = s_red[0] + s_red[1] + s_red[2] + s_red[3] + b2[0];
}

extern "C" void kernel_launch(void* const* d_in, const int* in_sizes, int n_in,
                              void* d_out, int out_size, void* d_ws, size_t ws_size,
                              hipStream_t stream) {
    const float* trg = (const float*)d_in[0];
    // d_in[1] = src: unused (n_layers = 0)
    const float* W1  = (const float*)d_in[2];
    const float* b1  = (const float*)d_in[3];
    const float* W2  = (const float*)d_in[4];
    const float* b2  = (const float*)d_in[5];
    float* out = (float*)d_out;

    // Workspace layout: m[B*NBLK] | l[B*NBLK] | pooled[B*NBLK*HID]
    float* ws_m = (float*)d_ws;
    float* ws_l = ws_m + BATCH * NBLK;
    float* ws_p = ws_l + BATCH * NBLK;

    pool_pass<<<dim3(BATCH * NBLK), THREADS, 0, stream>>>(trg, ws_m, ws_l, ws_p);
    finish_pass<<<dim3(BATCH), THREADS, 0, stream>>>(ws_m, ws_l, ws_p,
                                                     W1, b1, W2, b2, out);
}